// Round 13
// baseline (171.344 us; speedup 1.0000x reference)
//
#include <hip/hip_runtime.h>
#include <stdint.h>
#include <stddef.h>

// ---------------- problem constants ----------------
// B=2048, F0=39, D=16, layers 128/128/128, xk halves to 64 after each layer.
// Factored form: y_h[s,d] = sum_k W[h,k,s]*xk[b,k,d] (MFMA: A=W static, B=xk
// h-invariant -> register-cached per layer); z[b,s,d] = sum_h x0[b,h,d]*y_h[s,d].
// R24: R22 + wave de-phasing. Combine-elimination is closed (3 structures, 3
// failure modes: G-GEMM regalloc R14-17, fused coherence R20, u-GEMM LDS-BW
// R23: 16 waves re-reading a per-h u buffer = 160KB/step LDS = 1250cyc).
// R22 wall: matrix 620 + VALU 422 + LDS 370 ~= 1412 vs 1508 -> pipes DON'T
// overlap: all 4 waves/SIMD enter together and stay phase-locked (MfmaUtil 35
// + VALUBusy 28 = 63%). Fixes (scheduling-only, reg-neutral):
//  (1) s_setprio(1) around the MFMA+combine cluster — matches the attn case
//      (+4-7%, independent no-barrier waves), not the null lockstep case.
//  (2) stagger: waves with (wave>>2)&1==1 (odd waves ON EACH SIMD under
//      round-robin wave->SIMD) run the 4 bi-chains reversed; wave-uniform
//      branch, compile-time indices in both arms.
// Kept from R22: unroll 3, dist-1 W+xs prefetch, pk_fma combine, X0TS=45,
// flat-ih SALU walk, grid 256 (1 block/CU), bg-pair W sharing.
// Falsifiers: WRITE_SIZE must stay 2048KB, no slow dispatch-0, VGPR<=64.
#define F0N  39
#define SN   128
#define NB   8             // batches per block
#define X0TS 45            // f32 stride of X0T row (b,d): 39+6 pad, odd => conflict-free
#define XKTS 72            // u16 stride of XKT row (b,d): 64+8 pad, 16B-aligned
#define WBLK 8192          // u16 per (L,h) W block: 8 s-tiles x 2 chunks x 512
#define NHB2 234           // 3*39*2 prepass blocks (one per (L,h,k-half))

typedef __attribute__((ext_vector_type(8))) short short8;   // MFMA A/B operand
typedef __attribute__((ext_vector_type(4))) float floatx4;  // MFMA accumulator
typedef __attribute__((ext_vector_type(2))) float floatx2;  // pk_fma pair

__device__ __forceinline__ uint16_t f2bf(float f) {         // RNE f32->bf16
  uint32_t u = __float_as_uint(f);
  u += 0x7fffu + ((u >> 16) & 1u);
  return (uint16_t)(u >> 16);
}

// ---------------- pre-pass: W fp32 -> bf16 A-fragment blocks ----------------
// One block per (L,h,ch). Output layout identical to R6-R23 (verified):
//   wt[(L*39+h)*WBLK + (st*2+ch)*512 + lane*8 + j],
//   value = W[h][k=ch*32+quad*8+j][s=st*16+l16].
__global__ __launch_bounds__(256) void cin_prepass(
    const float* __restrict__ w0, const float* __restrict__ w1,
    const float* __restrict__ w2, uint16_t* __restrict__ wt) {
  __shared__ float T[32 * 132];               // [k_local][s], +4 pad floats/row
  const int bc = blockIdx.x;                  // 0..233
  const int ch = bc & 1;
  const int lh = bc >> 1;                     // 0..116
  const int L = lh / F0N;
  const int h = lh - L * F0N;
  const float* W = (L == 0) ? w0 : ((L == 1) ? w1 : w2);
  const int fk = (L == 0) ? 39 : 64;
  const int tid = threadIdx.x;

  for (int e = tid; e < 4096; e += 256) {     // coalesced fp32 read
    int kc = e >> 7, s = e & 127;
    int k = ch * 32 + kc;
    T[kc * 132 + s] = (k < fk) ? W[(h * fk + k) * SN + s] : 0.0f;
  }
  __syncthreads();
  uint32_t* dst = (uint32_t*)(wt + (size_t)lh * WBLK);
  for (int i = tid; i < 2048; i += 256) {     // coalesced u32 writes, frag order
    int st = i >> 8, w = i & 255;
    int ln = w >> 2, jp = w & 3;
    int quad = ln >> 4, l16 = ln & 15;
    int k0 = quad * 8 + jp * 2;               // local k within this half
    int s = st * 16 + l16;
    dst[(size_t)(st * 2 + ch) * 256 + w] =
        (uint32_t)f2bf(T[k0 * 132 + s]) | ((uint32_t)f2bf(T[(k0 + 1) * 132 + s]) << 16);
  }
}

// ---------------- fused main kernel ----------------
// 256 blocks x 1024 threads (16 waves), 1 block/CU, 4 waves/SIMD.
// Block owns NB=8 batches x full s (xk handoff block-local). Wave (st,bg):
// s-tile [st*16,st*16+16) x batches [bg*4, bg*4+4). Per layer: Bf register-
// cached; per h (unroll 3): dist-1 W prefetch (SALU ih base), dist-1 xs
// prefetch (layer rollover), prio-1 {8 MFMA + 8 pk_fma} in per-SIMD-staggered
// bi order. D-layout: D[s=st*16+quad*4+r][d=l16]; sum_d over l16 bits.
__global__ __launch_bounds__(1024) void cin_main(
    const float* __restrict__ x,       // (2048, 39, 16) fp32
    const float* __restrict__ bias0, const float* __restrict__ bias1,
    const float* __restrict__ bias2,
    const uint16_t* __restrict__ wt,   // A-frag bf16 weights (d_ws)
    float* __restrict__ out) {         // (2048, 256) fp32

  __shared__ __align__(16) float    X0T[NB * 16 * X0TS];  // x0[b][d][h] f32, 23040 B
  __shared__ __align__(16) uint16_t XKT[NB * 16 * XKTS];  // xk[b][d][k] bf16, 18432 B

  const int tid  = threadIdx.x;
  const int lane = tid & 63;
  const int wave = tid >> 6;           // 0..15
  const int st   = wave >> 1;          // s-tile 0..7
  const int bg   = wave & 1;           // batch group 0..1
  const int l16  = lane & 15;          // = d (output col)
  const int quad = lane >> 4;
  const int sk   = (wave >> 2) & 1;    // stagger key: alternates among the 4
                                       // waves of one SIMD (round-robin w->SIMD)
  const int bbase = blockIdx.x * NB;

  // zero X0T (h-pad 39..44 must be 0) and XKT (k-pad for L0)
  {
    float* p = X0T;
#pragma unroll
    for (int i = 0; i < 6; i++) { int e = tid + 1024 * i; if (e < NB * 16 * X0TS) p[e] = 0.f; }
    uint32_t* q = (uint32_t*)XKT;
#pragma unroll
    for (int i = 0; i < 5; i++) { int e = tid + 1024 * i; if (e < NB * 16 * XKTS / 2) q[e] = 0u; }
  }
  __syncthreads();

  // fill X0T[b][d][h] = x[bbase+b][h][d]  (coalesced read, LDS transpose-scatter)
#pragma unroll
  for (int it = 0; it < 5; ++it) {
    int e = tid + it * 1024;           // e = (b*39 + h)*16 + d, total 4992
    if (e < NB * F0N * 16) {
      float v = x[(size_t)bbase * (F0N * 16) + e];
      int d = e & 15, p = e >> 4;
      int b = p / F0N, h = p - b * F0N;
      X0T[(b * 16 + d) * X0TS + h] = v;
    }
  }
  __syncthreads();

  // build layer-0 XKT[b][d][k] = bf16(x0[b][k][d]) for k<39, 0 for k in [39,64)
  if (tid < 512) {
    int b = tid >> 6, d = (tid >> 2) & 15, kg = tid & 3;
    const float* src = &X0T[(b * 16 + d) * X0TS];
    uint32_t* drow = (uint32_t*)&XKT[(b * 16 + d) * XKTS + kg * 16];
#pragma unroll
    for (int i2 = 0; i2 < 8; i2++) {
      int k0 = kg * 16 + i2 * 2;
      uint32_t lo = (k0 < 39)     ? (uint32_t)f2bf(src[k0])     : 0u;
      uint32_t hi = (k0 + 1 < 39) ? (uint32_t)f2bf(src[k0 + 1]) : 0u;
      drow[i2] = lo | (hi << 16);
    }
  }
  __syncthreads();   // XKT build visible for Bf loads

  // per-lane constant W offset (u16 units) — bg-pair waves share lines (L1)
  const int stlane = st * 1024 + lane * 8;

  // per-(bi) x0 LDS element offsets (int, not pointers: 4 regs)
  int xoff[4];
#pragma unroll
  for (int bi = 0; bi < 4; ++bi)
    xoff[bi] = ((bg * 4 + bi) * 16 + l16) * X0TS;

  // seed dist-1 prefetches: ih = 0 (L0, h0); xs at h=0
  short8 Wc0 = *(const short8*)(wt + stlane);
  short8 Wc1 = *(const short8*)(wt + stlane + 512);
  float xsc[4];
#pragma unroll
  for (int bi = 0; bi < 4; ++bi) xsc[bi] = X0T[xoff[bi]];

  int ih = 0;                          // flat weight-block index = L*39 + h
#pragma unroll 1
  for (int L = 0; L < 3; ++L) {
    // register-cache B-fragments (h-invariant within layer); b = bg*4 + bi
    short8 Bf0[4], Bf1[4];
#pragma unroll
    for (int bi = 0; bi < 4; ++bi) {
      const uint16_t* r = XKT + ((bg * 4 + bi) * 16 + l16) * XKTS + quad * 8;
      Bf0[bi] = *(const short8*)r;          // k 0..31 chunk
      Bf1[bi] = *(const short8*)(r + 32);   // k 32..63 chunk
    }

    floatx4 z[4] = {};
    const floatx4 zero4 = {0.f, 0.f, 0.f, 0.f};

// one bi-chain: 2 MFMAs (K=64 via 2 chunks) + packed combine into z[bi]
#define MMSTEP(bi)                                                            \
    {                                                                         \
      floatx4 y = __builtin_amdgcn_mfma_f32_16x16x32_bf16(Wc0, Bf0[bi], zero4, 0, 0, 0); \
      y = __builtin_amdgcn_mfma_f32_16x16x32_bf16(Wc1, Bf1[bi], y, 0, 0, 0);  \
      floatx2 xv = {xsc[bi], xsc[bi]};                                        \
      floatx2* zp = (floatx2*)&z[bi];                                         \
      const floatx2* yp = (const floatx2*)&y;                                 \
      zp[0] += xv * yp[0];                                                    \
      zp[1] += xv * yp[1];                                                    \
    }

#pragma unroll 3
    for (int h = 0; h < 39; ++h, ++ih) {
      // dist-1 W prefetch; uniform SALU base (ih+1 at h=38 IS next layer's h0)
      int ihn = ih + 1;
      if (ihn > 116) ihn = 116;
      const uint16_t* wb = wt + (size_t)ihn * WBLK + stlane;
      short8 Wn0 = *(const short8*)(wb);
      short8 Wn1 = *(const short8*)(wb + 512);

      // dist-1 xs prefetch; x0 is layer-invariant so h=38 rolls to h=0
      int hn = (h == 38) ? 0 : h + 1;
      float xsn[4];
#pragma unroll
      for (int bi = 0; bi < 4; ++bi) xsn[bi] = X0T[xoff[bi] + hn];

      // prio-1 MFMA+combine cluster; per-SIMD staggered bi order (wave-
      // uniform branch, compile-time indices in both arms)
      __builtin_amdgcn_s_setprio(1);
      if (sk == 0) {
        MMSTEP(0) MMSTEP(1) MMSTEP(2) MMSTEP(3)
      } else {
        MMSTEP(3) MMSTEP(2) MMSTEP(1) MMSTEP(0)
      }
      __builtin_amdgcn_s_setprio(0);

      Wc0 = Wn0;
      Wc1 = Wn1;
#pragma unroll
      for (int bi = 0; bi < 4; ++bi) xsc[bi] = xsn[bi];
    }
#undef MMSTEP

    // ---- epilogue: bias (read here, not held across h-loop) + relu;
    //      xk handoff; sum_d (over l16) -> out ----
    const float* bp = (L == 0) ? bias0 : ((L == 1) ? bias1 : bias2);
#pragma unroll
    for (int bi = 0; bi < 4; ++bi) {
      const int b = bg * 4 + bi;
#pragma unroll
      for (int r = 0; r < 4; ++r) {
        float t = fmaxf(z[bi][r] + bp[st * 16 + quad * 4 + r], 0.f);
        if (L < 2 && st < 4)               // xk = relu(z)[:, :64]; k = s < 64
          XKT[(b * 16 + l16) * XKTS + st * 16 + quad * 4 + r] = f2bf(t);
        float s4 = t;                       // reduce over d = l16 (bits 0..3)
        s4 += __shfl_xor(s4, 1);
        s4 += __shfl_xor(s4, 2);
        s4 += __shfl_xor(s4, 4);
        s4 += __shfl_xor(s4, 8);
        if (l16 == 0) {
          int s = st * 16 + quad * 4 + r;
          // concat: L0 s64:128 -> 0:64 ; L1 s64:128 -> 64:128 ; L2 s -> 128:256
          if (L == 2)       out[(size_t)(bbase + b) * 256 + 128 + s] = s4;
          else if (s >= 64) out[(size_t)(bbase + b) * 256 + L * 64 + (s - 64)] = s4;
        }
      }
    }
    if (L < 2) __syncthreads();   // handoff writes visible before next-layer Bf loads
  }
}

extern "C" void kernel_launch(void* const* d_in, const int* in_sizes, int n_in,
                              void* d_out, int out_size, void* d_ws, size_t ws_size,
                              hipStream_t stream) {
  (void)in_sizes; (void)n_in; (void)out_size; (void)ws_size;
  const float* x  = (const float*)d_in[0];
  const float* w0 = (const float*)d_in[1];
  const float* b0 = (const float*)d_in[2];
  const float* w1 = (const float*)d_in[3];
  const float* b1 = (const float*)d_in[4];
  const float* w2 = (const float*)d_in[5];
  const float* b2 = (const float*)d_in[6];
  uint16_t* wt    = (uint16_t*)d_ws;   // 117 * 8192 * 2 = 1,916,928 B

  cin_prepass<<<NHB2, 256, 0, stream>>>(w0, w1, w2, wt);
  cin_main<<<256, 1024, 0, stream>>>(x, b0, b1, b2, wt, (float*)d_out);
}

// Round 14
// 137.167 us; speedup vs baseline: 1.2492x; 1.2492x over previous
//
#include <hip/hip_runtime.h>
#include <stdint.h>
#include <stddef.h>

// ---------------- problem constants ----------------
// B=2048, F0=39, D=16, layers 128/128/128, xk halves to 64 after each layer.
// Factored form: y_h[s,d] = sum_k W[h,k,s]*xk[b,k,d] (MFMA: A=W static, B=xk
// h-invariant -> register-cached per layer); z[b,s,d] = sum_h x0[b,h,d]*y_h[s,d].
// R25 = R22 verbatim (the session champion): steady main 73.5us, VGPR 64,
// zero spill, absmax 0.125. Final structure after 13 probe rounds:
//  - unroll 3 (39=13x3): reg rotation breaks the per-h WAR on y (R19/R21).
//  - dist-1 W prefetch via flat ih SALU base; dist-1 xs prefetch w/ layer
//    rollover (fits after bias moved to epilogue freed 4 regs, R21/R22).
//  - pk_fma combine (float2 -> v_pk_fma_f32), X0TS=45 odd stride (conflicts
//    4.69M -> 0.69M), grid 256 = 1 block/CU, bg-pair W sharing (L1).
// CLOSED lanes (each verified by counters):
//  - Combine-elimination: G-GEMM dies in regalloc (R14-17: alloc pins 60-64
//    arch VGPRs, AGPR-churn serializes); fused single-kernel dies on cross-
//    XCD coherence (R20: 223us); u-GEMM dies on LDS BW (R23: 16 waves x 8KB
//    re-read per h = 1250cyc/step).
//  - Occupancy: 2 blocks/CU thrashes the W stream (R12/R13: 87-90us).
//  - Scheduling: setprio+staggered cluster duplicates the MMSTEP arms ->
//    36MB loop-resident scratch spill (R24: 112us). Structure sits exactly
//    at the 64-VGPR boundary; any inner-loop shape change tips it over.
//  - Launch overhead: ~49us of the dur_us-main gap is harness reset() cost
//    (proven by R20's single-dispatch run); 2nd launch costs only ~6us.
// R22 wall: matrix-busy 25.7us == the 25us MFMA floor (62.7GF / 2.5PF);
// MfmaUtil 35 + VALU 28 with phase-locked waves is the HIP-source floor for
// this decomposition on gfx950.
#define F0N  39
#define SN   128
#define NB   8             // batches per block
#define X0TS 45            // f32 stride of X0T row (b,d): 39+6 pad, odd => conflict-free
#define XKTS 72            // u16 stride of XKT row (b,d): 64+8 pad, 16B-aligned
#define WBLK 8192          // u16 per (L,h) W block: 8 s-tiles x 2 chunks x 512
#define NHB2 234           // 3*39*2 prepass blocks (one per (L,h,k-half))

typedef __attribute__((ext_vector_type(8))) short short8;   // MFMA A/B operand
typedef __attribute__((ext_vector_type(4))) float floatx4;  // MFMA accumulator
typedef __attribute__((ext_vector_type(2))) float floatx2;  // pk_fma pair

__device__ __forceinline__ uint16_t f2bf(float f) {         // RNE f32->bf16
  uint32_t u = __float_as_uint(f);
  u += 0x7fffu + ((u >> 16) & 1u);
  return (uint16_t)(u >> 16);
}

// ---------------- pre-pass: W fp32 -> bf16 A-fragment blocks ----------------
// One block per (L,h,ch). Output layout identical to R6-R24 (verified):
//   wt[(L*39+h)*WBLK + (st*2+ch)*512 + lane*8 + j],
//   value = W[h][k=ch*32+quad*8+j][s=st*16+l16].
__global__ __launch_bounds__(256) void cin_prepass(
    const float* __restrict__ w0, const float* __restrict__ w1,
    const float* __restrict__ w2, uint16_t* __restrict__ wt) {
  __shared__ float T[32 * 132];               // [k_local][s], +4 pad floats/row
  const int bc = blockIdx.x;                  // 0..233
  const int ch = bc & 1;
  const int lh = bc >> 1;                     // 0..116
  const int L = lh / F0N;
  const int h = lh - L * F0N;
  const float* W = (L == 0) ? w0 : ((L == 1) ? w1 : w2);
  const int fk = (L == 0) ? 39 : 64;
  const int tid = threadIdx.x;

  for (int e = tid; e < 4096; e += 256) {     // coalesced fp32 read
    int kc = e >> 7, s = e & 127;
    int k = ch * 32 + kc;
    T[kc * 132 + s] = (k < fk) ? W[(h * fk + k) * SN + s] : 0.0f;
  }
  __syncthreads();
  uint32_t* dst = (uint32_t*)(wt + (size_t)lh * WBLK);
  for (int i = tid; i < 2048; i += 256) {     // coalesced u32 writes, frag order
    int st = i >> 8, w = i & 255;
    int ln = w >> 2, jp = w & 3;
    int quad = ln >> 4, l16 = ln & 15;
    int k0 = quad * 8 + jp * 2;               // local k within this half
    int s = st * 16 + l16;
    dst[(size_t)(st * 2 + ch) * 256 + w] =
        (uint32_t)f2bf(T[k0 * 132 + s]) | ((uint32_t)f2bf(T[(k0 + 1) * 132 + s]) << 16);
  }
}

// ---------------- fused main kernel ----------------
// 256 blocks x 1024 threads (16 waves), 1 block/CU, 4 waves/SIMD.
// Block owns NB=8 batches x full s (xk handoff block-local). Wave (st,bg):
// s-tile [st*16,st*16+16) x batches [bg*4, bg*4+4). Per layer: Bf register-
// cached; per h (unroll 3): dist-1 W prefetch (SALU ih base), dist-1 xs
// prefetch (layer rollover), 8 MFMA + 8 pk_fma. Flat weight index ih =
// L*39+h in [0,117); prefetch min(ih+1,116) rolls into next layer's h0 at
// h=38. D-layout: D[s=st*16+quad*4+r][d=l16]; sum_d over l16 bits.
__global__ __launch_bounds__(1024) void cin_main(
    const float* __restrict__ x,       // (2048, 39, 16) fp32
    const float* __restrict__ bias0, const float* __restrict__ bias1,
    const float* __restrict__ bias2,
    const uint16_t* __restrict__ wt,   // A-frag bf16 weights (d_ws)
    float* __restrict__ out) {         // (2048, 256) fp32

  __shared__ __align__(16) float    X0T[NB * 16 * X0TS];  // x0[b][d][h] f32, 23040 B
  __shared__ __align__(16) uint16_t XKT[NB * 16 * XKTS];  // xk[b][d][k] bf16, 18432 B

  const int tid  = threadIdx.x;
  const int lane = tid & 63;
  const int wave = tid >> 6;           // 0..15
  const int st   = wave >> 1;          // s-tile 0..7
  const int bg   = wave & 1;           // batch group 0..1
  const int l16  = lane & 15;          // = d (output col)
  const int quad = lane >> 4;
  const int bbase = blockIdx.x * NB;

  // zero X0T (h-pad 39..44 must be 0) and XKT (k-pad for L0)
  {
    float* p = X0T;
#pragma unroll
    for (int i = 0; i < 6; i++) { int e = tid + 1024 * i; if (e < NB * 16 * X0TS) p[e] = 0.f; }
    uint32_t* q = (uint32_t*)XKT;
#pragma unroll
    for (int i = 0; i < 5; i++) { int e = tid + 1024 * i; if (e < NB * 16 * XKTS / 2) q[e] = 0u; }
  }
  __syncthreads();

  // fill X0T[b][d][h] = x[bbase+b][h][d]  (coalesced read, LDS transpose-scatter)
#pragma unroll
  for (int it = 0; it < 5; ++it) {
    int e = tid + it * 1024;           // e = (b*39 + h)*16 + d, total 4992
    if (e < NB * F0N * 16) {
      float v = x[(size_t)bbase * (F0N * 16) + e];
      int d = e & 15, p = e >> 4;
      int b = p / F0N, h = p - b * F0N;
      X0T[(b * 16 + d) * X0TS + h] = v;
    }
  }
  __syncthreads();

  // build layer-0 XKT[b][d][k] = bf16(x0[b][k][d]) for k<39, 0 for k in [39,64)
  if (tid < 512) {
    int b = tid >> 6, d = (tid >> 2) & 15, kg = tid & 3;
    const float* src = &X0T[(b * 16 + d) * X0TS];
    uint32_t* drow = (uint32_t*)&XKT[(b * 16 + d) * XKTS + kg * 16];
#pragma unroll
    for (int i2 = 0; i2 < 8; i2++) {
      int k0 = kg * 16 + i2 * 2;
      uint32_t lo = (k0 < 39)     ? (uint32_t)f2bf(src[k0])     : 0u;
      uint32_t hi = (k0 + 1 < 39) ? (uint32_t)f2bf(src[k0 + 1]) : 0u;
      drow[i2] = lo | (hi << 16);
    }
  }
  __syncthreads();   // XKT build visible for Bf loads

  // per-lane constant W offset (u16 units) — bg-pair waves share lines (L1)
  const int stlane = st * 1024 + lane * 8;

  // per-(bi) x0 LDS element offsets (int, not pointers: 4 regs)
  int xoff[4];
#pragma unroll
  for (int bi = 0; bi < 4; ++bi)
    xoff[bi] = ((bg * 4 + bi) * 16 + l16) * X0TS;

  // seed dist-1 prefetches: ih = 0 (L0, h0); xs at h=0
  short8 Wc0 = *(const short8*)(wt + stlane);
  short8 Wc1 = *(const short8*)(wt + stlane + 512);
  float xsc[4];
#pragma unroll
  for (int bi = 0; bi < 4; ++bi) xsc[bi] = X0T[xoff[bi]];

  int ih = 0;                          // flat weight-block index = L*39 + h
#pragma unroll 1
  for (int L = 0; L < 3; ++L) {
    // register-cache B-fragments (h-invariant within layer); b = bg*4 + bi
    short8 Bf0[4], Bf1[4];
#pragma unroll
    for (int bi = 0; bi < 4; ++bi) {
      const uint16_t* r = XKT + ((bg * 4 + bi) * 16 + l16) * XKTS + quad * 8;
      Bf0[bi] = *(const short8*)r;          // k 0..31 chunk
      Bf1[bi] = *(const short8*)(r + 32);   // k 32..63 chunk
    }

    floatx4 z[4] = {};
    const floatx4 zero4 = {0.f, 0.f, 0.f, 0.f};

#pragma unroll 3
    for (int h = 0; h < 39; ++h, ++ih) {
      // dist-1 W prefetch; uniform SALU base (ih+1 at h=38 IS next layer's h0)
      int ihn = ih + 1;
      if (ihn > 116) ihn = 116;
      const uint16_t* wb = wt + (size_t)ihn * WBLK + stlane;
      short8 Wn0 = *(const short8*)(wb);
      short8 Wn1 = *(const short8*)(wb + 512);

      // dist-1 xs prefetch; x0 is layer-invariant so h=38 rolls to h=0
      int hn = (h == 38) ? 0 : h + 1;
      float xsn[4];
#pragma unroll
      for (int bi = 0; bi < 4; ++bi) xsn[bi] = X0T[xoff[bi] + hn];

#pragma unroll
      for (int bi = 0; bi < 4; ++bi) {
        floatx4 y = __builtin_amdgcn_mfma_f32_16x16x32_bf16(Wc0, Bf0[bi], zero4, 0, 0, 0);
        y = __builtin_amdgcn_mfma_f32_16x16x32_bf16(Wc1, Bf1[bi], y, 0, 0, 0);
        // packed combine: float2 ops -> v_pk_fma_f32 (8 instead of 16 fmac)
        floatx2 xv = {xsc[bi], xsc[bi]};
        floatx2* zp = (floatx2*)&z[bi];
        const floatx2* yp = (const floatx2*)&y;
        zp[0] += xv * yp[0];
        zp[1] += xv * yp[1];
      }
      Wc0 = Wn0;
      Wc1 = Wn1;
#pragma unroll
      for (int bi = 0; bi < 4; ++bi) xsc[bi] = xsn[bi];
    }

    // ---- epilogue: bias (read here, not held across h-loop) + relu;
    //      xk handoff; sum_d (over l16) -> out ----
    const float* bp = (L == 0) ? bias0 : ((L == 1) ? bias1 : bias2);
#pragma unroll
    for (int bi = 0; bi < 4; ++bi) {
      const int b = bg * 4 + bi;
#pragma unroll
      for (int r = 0; r < 4; ++r) {
        float t = fmaxf(z[bi][r] + bp[st * 16 + quad * 4 + r], 0.f);
        if (L < 2 && st < 4)               // xk = relu(z)[:, :64]; k = s < 64
          XKT[(b * 16 + l16) * XKTS + st * 16 + quad * 4 + r] = f2bf(t);
        float s4 = t;                       // reduce over d = l16 (bits 0..3)
        s4 += __shfl_xor(s4, 1);
        s4 += __shfl_xor(s4, 2);
        s4 += __shfl_xor(s4, 4);
        s4 += __shfl_xor(s4, 8);
        if (l16 == 0) {
          int s = st * 16 + quad * 4 + r;
          // concat: L0 s64:128 -> 0:64 ; L1 s64:128 -> 64:128 ; L2 s -> 128:256
          if (L == 2)       out[(size_t)(bbase + b) * 256 + 128 + s] = s4;
          else if (s >= 64) out[(size_t)(bbase + b) * 256 + L * 64 + (s - 64)] = s4;
        }
      }
    }
    if (L < 2) __syncthreads();   // handoff writes visible before next-layer Bf loads
  }
}

extern "C" void kernel_launch(void* const* d_in, const int* in_sizes, int n_in,
                              void* d_out, int out_size, void* d_ws, size_t ws_size,
                              hipStream_t stream) {
  (void)in_sizes; (void)n_in; (void)out_size; (void)ws_size;
  const float* x  = (const float*)d_in[0];
  const float* w0 = (const float*)d_in[1];
  const float* b0 = (const float*)d_in[2];
  const float* w1 = (const float*)d_in[3];
  const float* b1 = (const float*)d_in[4];
  const float* w2 = (const float*)d_in[5];
  const float* b2 = (const float*)d_in[6];
  uint16_t* wt    = (uint16_t*)d_ws;   // 117 * 8192 * 2 = 1,916,928 B

  cin_prepass<<<NHB2, 256, 0, stream>>>(w0, w1, w2, wt);
  cin_main<<<256, 1024, 0, stream>>>(x, b0, b1, b2, wt, (float*)d_out);
}